// Round 3
// baseline (188.233 us; speedup 1.0000x reference)
//
#include <hip/hip_runtime.h>
#include <hip/hip_bf16.h>

#define TB 8
#define TT 2048
#define TC 1024
#define TH 64

typedef __bf16 bf16;
typedef __bf16 bf16x4 __attribute__((ext_vector_type(4)));
typedef __bf16 bf16x8 __attribute__((ext_vector_type(8)));
typedef float  f32x4  __attribute__((ext_vector_type(4)));

// softmax scale folded with log2(e): attn uses exp2 instead of exp
constexpr float QSCALE = 0.125f * 1.44269504088896340736f;

// ---------------------------------------------------------------------------
// Kernel 1: transpose + cast weights: w_{q,k,v}[1024][64] fp32 -> wT[3][64][1024] bf16
// ---------------------------------------------------------------------------
__global__ void prep_wT(const float* __restrict__ wq, const float* __restrict__ wk,
                        const float* __restrict__ wv, bf16* __restrict__ wT) {
    int idx = blockIdx.x * blockDim.x + threadIdx.x;
    if (idx >= 3 * TH * TC) return;
    int wsel = idx / (TH * TC);
    int rem  = idx % (TH * TC);
    int c = rem / TH;
    int h = rem % TH;
    const float* w = (wsel == 0) ? wq : (wsel == 1) ? wk : wv;
    wT[(size_t)wsel * TH * TC + (size_t)h * TC + c] = (bf16)w[(size_t)c * TH + h];
}

// ---------------------------------------------------------------------------
// Kernel 2: QKV projection, K-split 2. Wave = (16 rows, half of C=1024).
// 2048 single-wave blocks -> 8 waves/CU. x prefetch ring depth 4 (8 KB in
// flight/wave), wT B-frags double-buffered. Writes fp32 partials P[2][M][192].
// ---------------------------------------------------------------------------
__launch_bounds__(64)
__global__ void proj_qkv(const float* __restrict__ x, const bf16* __restrict__ wT,
                         float* __restrict__ P) {
    const int lane = threadIdx.x;
    const int quad = lane >> 4, l16 = lane & 15;
    const int rt = blockIdx.x >> 1;     // row tile (16 rows)
    const int s  = blockIdx.x & 1;      // K-split half
    const int m0 = rt * 16;

    const float* xp = x  + (size_t)(m0 + l16) * TC + s * 512 + quad * 8;
    const bf16*  wp = wT + s * 512 + quad * 8;

    f32x4 acc[12];
#pragma unroll
    for (int i = 0; i < 12; i++) acc[i] = f32x4{0.f, 0.f, 0.f, 0.f};

    // prologue: x ring depth 4, B ring depth 2
    float4 xa[4][2];
#pragma unroll
    for (int p = 0; p < 4; p++) {
        xa[p][0] = ((const float4*)(xp + p * 32))[0];
        xa[p][1] = ((const float4*)(xp + p * 32))[1];
    }
    bf16x8 bb[2][12];
#pragma unroll
    for (int p = 0; p < 2; p++)
#pragma unroll
        for (int g = 0; g < 12; g++)
            bb[p][g] = *(const bf16x8*)(wp + (size_t)(g * 16 + l16) * TC + p * 32);

#pragma unroll
    for (int kc = 0; kc < 16; kc++) {
        const int xs = kc & 3, bs = kc & 1;
        bf16x8 af;
        af[0] = (bf16)xa[xs][0].x; af[1] = (bf16)xa[xs][0].y;
        af[2] = (bf16)xa[xs][0].z; af[3] = (bf16)xa[xs][0].w;
        af[4] = (bf16)xa[xs][1].x; af[5] = (bf16)xa[xs][1].y;
        af[6] = (bf16)xa[xs][1].z; af[7] = (bf16)xa[xs][1].w;
#pragma unroll
        for (int g = 0; g < 12; g++)
            acc[g] = __builtin_amdgcn_mfma_f32_16x16x32_bf16(af, bb[bs][g], acc[g], 0, 0, 0);
        // refill rings
        if (kc + 4 < 16) {
            xa[xs][0] = ((const float4*)(xp + (kc + 4) * 32))[0];
            xa[xs][1] = ((const float4*)(xp + (kc + 4) * 32))[1];
        }
        if (kc + 2 < 16) {
#pragma unroll
            for (int g = 0; g < 12; g++)
                bb[bs][g] = *(const bf16x8*)(wp + (size_t)(g * 16 + l16) * TC + (kc + 2) * 32);
        }
    }

    // epilogue: fp32 partials, P[s][m][col], col = g*16+l16, m = m0+quad*4+r
    float* Pp = P + ((size_t)s * (TB * TT) + (m0 + quad * 4)) * 192;
#pragma unroll
    for (int g = 0; g < 12; g++) {
        int col = g * 16 + l16;
#pragma unroll
        for (int r = 0; r < 4; r++)
            Pp[(size_t)r * 192 + col] = acc[g][r];
    }
}

// ---------------------------------------------------------------------------
// Kernel 2b: combine partials -> Q (scaled), K, VT (transposed via LDS).
// Block = 32 rows of M. 512 blocks x 256 threads.
// ---------------------------------------------------------------------------
__launch_bounds__(256)
__global__ void combine(const float* __restrict__ P, bf16* __restrict__ Q,
                        bf16* __restrict__ K, bf16* __restrict__ VT) {
    __shared__ bf16 T[64][34];   // [h][t] tile, +2 pad
    const int tid = threadIdx.x;
    const int m0  = blockIdx.x * 32;
    const float* P0 = P + (size_t)m0 * 192;
    const float* P1 = P + (size_t)(TB * TT) * 192 + (size_t)m0 * 192;

    // ---- Q/K phase: cols 0..127 ----
    {
        const int c4 = tid & 31, mr = tid >> 5;   // 8 m per pass
#pragma unroll
        for (int p = 0; p < 4; p++) {
            int m = mr + p * 8;
            float4 a = *(const float4*)(P0 + (size_t)m * 192 + c4 * 4);
            float4 bq = *(const float4*)(P1 + (size_t)m * 192 + c4 * 4);
            float sc = (c4 < 16) ? QSCALE : 1.0f;
            bf16x4 o;
            o[0] = (bf16)((a.x + bq.x) * sc); o[1] = (bf16)((a.y + bq.y) * sc);
            o[2] = (bf16)((a.z + bq.z) * sc); o[3] = (bf16)((a.w + bq.w) * sc);
            size_t gm = m0 + m;
            if (c4 < 16) *(bf16x4*)(Q + gm * TH + c4 * 4) = o;
            else         *(bf16x4*)(K + gm * TH + (c4 - 16) * 4) = o;
        }
    }

    // ---- V phase: cols 128..191 -> LDS transpose -> VT ----
    {
        const int c4 = tid & 15, mr = tid >> 4;   // 16 m per pass
#pragma unroll
        for (int p = 0; p < 2; p++) {
            int m = mr + p * 16;
            float4 a = *(const float4*)(P0 + (size_t)m * 192 + 128 + c4 * 4);
            float4 bq = *(const float4*)(P1 + (size_t)m * 192 + 128 + c4 * 4);
            T[c4 * 4 + 0][m] = (bf16)(a.x + bq.x);
            T[c4 * 4 + 1][m] = (bf16)(a.y + bq.y);
            T[c4 * 4 + 2][m] = (bf16)(a.z + bq.z);
            T[c4 * 4 + 3][m] = (bf16)(a.w + bq.w);
        }
    }
    __syncthreads();
    {
        const int h = tid >> 2, seg = tid & 3;    // 8 t x 2B = 16 B per thread
        const int b = m0 >> 11, t0 = m0 & 2047;
        bf16x8 o;
#pragma unroll
        for (int i = 0; i < 8; i++) o[i] = T[h][seg * 8 + i];
        *(bf16x8*)(VT + ((size_t)b * TH + h) * TT + t0 + seg * 8) = o;
    }
}

// ---------------------------------------------------------------------------
// Kernel 3: causal flash attention (unchanged from round 2).
// ---------------------------------------------------------------------------
#define LDP 72
#define NW 4

__launch_bounds__(256)
__global__ void attn(const bf16* __restrict__ Q, const bf16* __restrict__ K,
                     const bf16* __restrict__ VT, float* __restrict__ out) {
    __shared__ __align__(16) union SM {
        bf16 P[NW][2][16][LDP];
        struct { float O[NW][16][68]; float M[NW][16]; float L[NW][16]; } mg;
    } sm;

    const int tid  = threadIdx.x;
    const int wv   = tid >> 6;
    const int lane = tid & 63;
    const int quad = lane >> 4, l16 = lane & 15;
    const int b  = blockIdx.x & 7;
    const int rt = 127 - (blockIdx.x >> 3);
    const int q0 = rt * 16;
    const int ktmax = rt >> 2;

    const bf16* Qb = Q  + (size_t)b * TT * TH;
    const bf16* Kb = K  + (size_t)b * TT * TH;
    const bf16* Vb = VT + (size_t)b * TH * TT;

    bf16x8 bq0, bq1;
    {
        const bf16* qp = Qb + (size_t)(q0 + l16) * TH + quad * 8;
        bq0 = *(const bf16x8*)qp;
        bq1 = *(const bf16x8*)(qp + 32);
    }

    f32x4 accO[4];
#pragma unroll
    for (int g = 0; g < 4; g++) accO[g] = f32x4{0.f, 0.f, 0.f, 0.f};
    float mI = -1e30f, lI = 0.f;

    int nit = 0;
    for (int kt = wv; kt <= ktmax; kt += NW, nit++) {
        const int k0 = kt * 64;

        f32x4 s[4];
#pragma unroll
        for (int g = 0; g < 4; g++) {
            const bf16* kp = Kb + (size_t)(k0 + g * 16 + l16) * TH + quad * 8;
            bf16x8 ka0 = *(const bf16x8*)kp;
            bf16x8 ka1 = *(const bf16x8*)(kp + 32);
            f32x4 t = f32x4{0.f, 0.f, 0.f, 0.f};
            t = __builtin_amdgcn_mfma_f32_16x16x32_bf16(ka0, bq0, t, 0, 0, 0);
            t = __builtin_amdgcn_mfma_f32_16x16x32_bf16(ka1, bq1, t, 0, 0, 0);
            s[g] = t;
        }

        if (kt == ktmax) {
            const int qrel = ((rt & 3) << 4) + l16;
#pragma unroll
            for (int g = 0; g < 4; g++)
#pragma unroll
                for (int r = 0; r < 4; r++)
                    if (g * 16 + quad * 4 + r > qrel) s[g][r] = -3.0e38f;
        }

        float mx = s[0][0];
#pragma unroll
        for (int g = 0; g < 4; g++)
#pragma unroll
            for (int r = 0; r < 4; r++) mx = fmaxf(mx, s[g][r]);
        mx = fmaxf(mx, __shfl_xor(mx, 16));
        mx = fmaxf(mx, __shfl_xor(mx, 32));
        float mnew  = fmaxf(mI, mx);
        float alpha = exp2f(mI - mnew);
        mI = mnew;
        float rs = 0.f;
#pragma unroll
        for (int g = 0; g < 4; g++)
#pragma unroll
            for (int r = 0; r < 4; r++) {
                float p = exp2f(s[g][r] - mnew);
                s[g][r] = p;
                rs += p;
            }
        rs += __shfl_xor(rs, 16);
        rs += __shfl_xor(rs, 32);
        lI = lI * alpha + rs;

        float arow[4];
#pragma unroll
        for (int r = 0; r < 4; r++) arow[r] = __shfl(alpha, quad * 4 + r);
#pragma unroll
        for (int g = 0; g < 4; g++)
#pragma unroll
            for (int r = 0; r < 4; r++) accO[g][r] *= arow[r];

        const int par = nit & 1;
#pragma unroll
        for (int g = 0; g < 4; g++) {
            bf16x4 pk;
            pk[0] = (bf16)s[g][0]; pk[1] = (bf16)s[g][1];
            pk[2] = (bf16)s[g][2]; pk[3] = (bf16)s[g][3];
            *(bf16x4*)(&sm.P[wv][par][l16][g * 16 + quad * 4]) = pk;
        }
        __threadfence_block();

#pragma unroll
        for (int c = 0; c < 2; c++) {
            bf16x8 ap = *(const bf16x8*)(&sm.P[wv][par][l16][c * 32 + quad * 8]);
#pragma unroll
            for (int g = 0; g < 4; g++) {
                const bf16* vp = Vb + (size_t)(g * 16 + l16) * TT + k0 + c * 32 + quad * 8;
                bf16x8 bv = *(const bf16x8*)vp;
                accO[g] = __builtin_amdgcn_mfma_f32_16x16x32_bf16(ap, bv, accO[g], 0, 0, 0);
            }
        }
    }

    __syncthreads();
#pragma unroll
    for (int g = 0; g < 4; g++)
#pragma unroll
        for (int r = 0; r < 4; r++)
            sm.mg.O[wv][quad * 4 + r][g * 16 + l16] = accO[g][r];
    if (lane < 16) {
        sm.mg.M[wv][lane] = mI;
        sm.mg.L[wv][lane] = lI;
    }
    __syncthreads();

    {
        const int q = tid >> 4;
        const int h = (tid & 15) * 4;
        float gm = sm.mg.M[0][q];
#pragma unroll
        for (int w = 1; w < NW; w++) gm = fmaxf(gm, sm.mg.M[w][q]);
        float denom = 0.f, o0 = 0.f, o1 = 0.f, o2 = 0.f, o3 = 0.f;
#pragma unroll
        for (int w = 0; w < NW; w++) {
            float sc = exp2f(sm.mg.M[w][q] - gm);
            denom += sm.mg.L[w][q] * sc;
            o0 += sm.mg.O[w][q][h + 0] * sc;
            o1 += sm.mg.O[w][q][h + 1] * sc;
            o2 += sm.mg.O[w][q][h + 2] * sc;
            o3 += sm.mg.O[w][q][h + 3] * sc;
        }
        float inv = 1.f / denom;
        float4 res = make_float4(o0 * inv, o1 * inv, o2 * inv, o3 * inv);
        *(float4*)(out + ((size_t)b * TT + q0 + q) * TH + h) = res;
    }
}

// ---------------------------------------------------------------------------
extern "C" void kernel_launch(void* const* d_in, const int* in_sizes, int n_in,
                              void* d_out, int out_size, void* d_ws, size_t ws_size,
                              hipStream_t stream) {
    const float* x  = (const float*)d_in[0];
    const float* wq = (const float*)d_in[1];
    const float* wk = (const float*)d_in[2];
    const float* wv = (const float*)d_in[3];

    char* ws = (char*)d_ws;
    bf16*  wT = (bf16*)(ws);                        // 393216 B
    bf16*  Q  = (bf16*)(ws + 393216);               // 2 MB
    bf16*  K  = (bf16*)(ws + 2490368);              // 2 MB
    bf16*  VT = (bf16*)(ws + 4587520);              // 2 MB
    float* P  = (float*)(ws + 6684672);             // 2*16384*192*4 = 25.2 MB
    float* out = (float*)d_out;

    hipLaunchKernelGGL(prep_wT, dim3(768), dim3(256), 0, stream, wq, wk, wv, wT);
    hipLaunchKernelGGL(proj_qkv, dim3(2048), dim3(64), 0, stream, x, wT, P);
    hipLaunchKernelGGL(combine, dim3(512), dim3(256), 0, stream, P, Q, K, VT);
    hipLaunchKernelGGL(attn, dim3(TB * 128), dim3(256), 0, stream, Q, K, VT, out);
}